// Round 1
// baseline (362.955 us; speedup 1.0000x reference)
//
#include <hip/hip_runtime.h>
#include <hip/hip_bf16.h>

// SparseConvTranspose: gather-GEMM-scatter via bf16 MFMA.
// feats [100000,64] f32, weight [27,64,32] f32, in_map/out_map [27,100000] int32,
// out [400000,32] f32 (scatter-add).

using short8  = __attribute__((ext_vector_type(8))) short;
using floatx4 = __attribute__((ext_vector_type(4))) float;

constexpr int KOFF = 27;
constexpr int NIN  = 100000;
constexpr int CIN  = 64;
constexpr int COUT = 32;
constexpr int MSGS = NIN;            // messages per kernel offset
constexpr int TILES = MSGS / 16;     // 6250 16-message tiles per offset (exact)
constexpr int WAVES_PER_BLOCK = 4;

// round-to-nearest-even f32 -> bf16 bits
__device__ __forceinline__ short f2bf(float f) {
    union { float f; unsigned u; } v; v.f = f;
    unsigned r = v.u + 0x7fff + ((v.u >> 16) & 1u);
    return (short)(r >> 16);
}

__global__ __launch_bounds__(256) void spconv_mfma_kernel(
    const float* __restrict__ feats,
    const float* __restrict__ weight,
    const int*   __restrict__ in_map,
    const int*   __restrict__ out_map,
    float*       __restrict__ out)
{
    const int k    = blockIdx.y;                 // kernel offset 0..26
    const int wave = threadIdx.x >> 6;
    const int lane = threadIdx.x & 63;
    const int col  = lane & 15;                  // n (and A-row m) index
    const int quad = lane >> 4;                  // 0..3

    const int tile = blockIdx.x * WAVES_PER_BLOCK + wave;  // 16-msg tile
    if (tile >= TILES) return;
    const int m0 = tile * 16;

    const long long mapbase = (long long)k * MSGS;

    // ---- B fragments for this k: fp32 -> bf16, registers only ----
    // B[kk = quad*8+j + 32*s][n = t*16 + col]
    const float* Wk = weight + k * (CIN * COUT);
    short8 bfr[2][2];                            // [kstep][coltile]
    #pragma unroll
    for (int s = 0; s < 2; ++s)
        #pragma unroll
        for (int t = 0; t < 2; ++t)
            #pragma unroll
            for (int j = 0; j < 8; ++j)
                bfr[s][t][j] = f2bf(Wk[(s * 32 + quad * 8 + j) * COUT + t * 16 + col]);

    // ---- gather A fragment: A[m = lane&15][kk = quad*8+j (+32*s)] ----
    const int myrow  = m0 + col;                 // message id for my A row
    const int in_row = in_map[mapbase + myrow];
    const float* arow = feats + (long long)in_row * CIN + quad * 8;

    floatx4 acc0 = {0.f, 0.f, 0.f, 0.f};
    floatx4 acc1 = {0.f, 0.f, 0.f, 0.f};
    #pragma unroll
    for (int s = 0; s < 2; ++s) {
        const float4* p = (const float4*)(arow + s * 32);
        float4 lo = p[0];
        float4 hi = p[1];
        short8 a;
        a[0] = f2bf(lo.x); a[1] = f2bf(lo.y); a[2] = f2bf(lo.z); a[3] = f2bf(lo.w);
        a[4] = f2bf(hi.x); a[5] = f2bf(hi.y); a[6] = f2bf(hi.z); a[7] = f2bf(hi.w);
        acc0 = __builtin_amdgcn_mfma_f32_16x16x32_bf16(a, bfr[s][0], acc0, 0, 0, 0);
        acc1 = __builtin_amdgcn_mfma_f32_16x16x32_bf16(a, bfr[s][1], acc1, 0, 0, 0);
    }

    // ---- scatter-add epilogue ----
    // C/D layout: col = lane&15, row = quad*4 + i  (measured m89/m91)
    #pragma unroll
    for (int i = 0; i < 4; ++i) {
        const int m    = m0 + quad * 4 + i;
        const int orow = out_map[mapbase + m];
        float* po = out + (long long)orow * COUT;
        atomicAdd(po + col,      acc0[i]);
        atomicAdd(po + col + 16, acc1[i]);
    }
}

extern "C" void kernel_launch(void* const* d_in, const int* in_sizes, int n_in,
                              void* d_out, int out_size, void* d_ws, size_t ws_size,
                              hipStream_t stream) {
    const float* feats   = (const float*)d_in[0];
    const float* weight  = (const float*)d_in[1];
    const int*   in_map  = (const int*)d_in[2];
    const int*   out_map = (const int*)d_in[3];
    float*       out     = (float*)d_out;

    // harness re-poisons d_out to 0xAA before every timed launch: zero it here
    hipMemsetAsync(d_out, 0, (size_t)out_size * sizeof(float), stream);

    dim3 grid((TILES + WAVES_PER_BLOCK - 1) / WAVES_PER_BLOCK, KOFF);
    dim3 block(WAVES_PER_BLOCK * 64);
    spconv_mfma_kernel<<<grid, block, 0, stream>>>(feats, weight, in_map, out_map, out);
}

// Round 2
// 267.600 us; speedup vs baseline: 1.3563x; 1.3563x over previous
//
#include <hip/hip_runtime.h>
#include <hip/hip_bf16.h>
#include <hip/hip_fp16.h>

// SparseConvTranspose: gather-MFMA-scatter.
// Round 2: fp16 packed-atomic accumulation (halves scatter write-through) +
// bf16 pre-converted feats (halves gather bytes). f32 result materialized by a
// final convert kernel. Runtime fallbacks if ws_size is too small.

using short8  = __attribute__((ext_vector_type(8))) short;
using floatx4 = __attribute__((ext_vector_type(4))) float;

constexpr int KOFF = 27;
constexpr int NIN  = 100000;
constexpr int NOUT = 400000;
constexpr int CIN  = 64;
constexpr int COUT = 32;
constexpr int MSGS = NIN;
constexpr int TILES = MSGS / 16;     // 6250
constexpr int WPB   = 4;             // waves per block

constexpr size_t ACC_BYTES   = (size_t)NOUT * COUT * 2;  // 25.6 MB fp16 accum
constexpr size_t FEATS_BYTES = (size_t)NIN * CIN * 2;    // 12.8 MB bf16 feats

// round-to-nearest-even f32 -> bf16 bits
__device__ __forceinline__ short f2bf(float f) {
    union { float f; unsigned u; } v; v.f = f;
    unsigned r = v.u + 0x7fff + ((v.u >> 16) & 1u);
    return (short)(r >> 16);
}

// ---------------- main kernel: fp16 packed-atomic accumulation -------------
// B-frag t holds physical out-column 2*col+t, so each lane owns an adjacent
// (even,odd) column pair -> one global_atomic_pk_add_f16 per (lane, i).
template<bool BF16F>
__global__ __launch_bounds__(256) void spconv_fp16acc_kernel(
    const float*  __restrict__ feats_f32,
    const ushort* __restrict__ feats_bf,
    const float*  __restrict__ weight,
    const int*    __restrict__ in_map,
    const int*    __restrict__ out_map,
    __half2*      __restrict__ accum)     // [NOUT * 16] half2
{
    const int k    = blockIdx.y;
    const int wave = threadIdx.x >> 6;
    const int lane = threadIdx.x & 63;
    const int col  = lane & 15;
    const int quad = lane >> 4;

    const int tile = blockIdx.x * WPB + wave;
    if (tile >= TILES) return;
    const int m0 = tile * 16;
    const long long mapbase = (long long)k * MSGS;

    // independent map loads first (ILP)
    const int in_row = in_map[mapbase + m0 + col];
    int orow[4];
    #pragma unroll
    for (int i = 0; i < 4; ++i) orow[i] = out_map[mapbase + m0 + quad * 4 + i];

    // B fragments: bfr[s][t][j] = W[k][s*32+quad*8+j][2*col+t]
    const float* Wk = weight + k * (CIN * COUT);
    short8 bfr[2][2];
    #pragma unroll
    for (int s = 0; s < 2; ++s)
        #pragma unroll
        for (int t = 0; t < 2; ++t)
            #pragma unroll
            for (int j = 0; j < 8; ++j)
                bfr[s][t][j] = f2bf(Wk[(s * 32 + quad * 8 + j) * COUT + 2 * col + t]);

    // A fragments: A[m=col][kk=quad*8+j (+32*s)]
    short8 a0, a1;
    if (BF16F) {
        const ushort* ar = feats_bf + (long long)in_row * CIN;
        a0 = *(const short8*)(ar + quad * 8);          // 16B aligned
        a1 = *(const short8*)(ar + 32 + quad * 8);
    } else {
        const float* ar = feats_f32 + (long long)in_row * CIN + quad * 8;
        const float4* p0 = (const float4*)ar;
        const float4* p1 = (const float4*)(ar + 32);
        float4 l0 = p0[0], h0 = p0[1], l1 = p1[0], h1 = p1[1];
        a0[0]=f2bf(l0.x); a0[1]=f2bf(l0.y); a0[2]=f2bf(l0.z); a0[3]=f2bf(l0.w);
        a0[4]=f2bf(h0.x); a0[5]=f2bf(h0.y); a0[6]=f2bf(h0.z); a0[7]=f2bf(h0.w);
        a1[0]=f2bf(l1.x); a1[1]=f2bf(l1.y); a1[2]=f2bf(l1.z); a1[3]=f2bf(l1.w);
        a1[4]=f2bf(h1.x); a1[5]=f2bf(h1.y); a1[6]=f2bf(h1.z); a1[7]=f2bf(h1.w);
    }

    floatx4 acc0 = {0.f, 0.f, 0.f, 0.f};
    floatx4 acc1 = {0.f, 0.f, 0.f, 0.f};
    acc0 = __builtin_amdgcn_mfma_f32_16x16x32_bf16(a0, bfr[0][0], acc0, 0, 0, 0);
    acc1 = __builtin_amdgcn_mfma_f32_16x16x32_bf16(a0, bfr[0][1], acc1, 0, 0, 0);
    acc0 = __builtin_amdgcn_mfma_f32_16x16x32_bf16(a1, bfr[1][0], acc0, 0, 0, 0);
    acc1 = __builtin_amdgcn_mfma_f32_16x16x32_bf16(a1, bfr[1][1], acc1, 0, 0, 0);

    // scatter: C/D layout col=lane&15, row=quad*4+i; lane owns cols (2c, 2c+1)
    #pragma unroll
    for (int i = 0; i < 4; ++i) {
        __half2 h = __floats2half2_rn(acc0[i], acc1[i]);
        unsafeAtomicAdd(accum + (long long)orow[i] * 16 + col, h);
    }
}

// ---------------- fallback: round-1 kernel (f32 atomics into d_out) --------
__global__ __launch_bounds__(256) void spconv_f32atomic_kernel(
    const float* __restrict__ feats,
    const float* __restrict__ weight,
    const int*   __restrict__ in_map,
    const int*   __restrict__ out_map,
    float*       __restrict__ out)
{
    const int k    = blockIdx.y;
    const int wave = threadIdx.x >> 6;
    const int lane = threadIdx.x & 63;
    const int col  = lane & 15;
    const int quad = lane >> 4;
    const int tile = blockIdx.x * WPB + wave;
    if (tile >= TILES) return;
    const int m0 = tile * 16;
    const long long mapbase = (long long)k * MSGS;

    const float* Wk = weight + k * (CIN * COUT);
    short8 bfr[2][2];
    #pragma unroll
    for (int s = 0; s < 2; ++s)
        #pragma unroll
        for (int t = 0; t < 2; ++t)
            #pragma unroll
            for (int j = 0; j < 8; ++j)
                bfr[s][t][j] = f2bf(Wk[(s * 32 + quad * 8 + j) * COUT + t * 16 + col]);

    const int in_row = in_map[mapbase + m0 + col];
    const float* arow = feats + (long long)in_row * CIN + quad * 8;

    floatx4 acc0 = {0.f, 0.f, 0.f, 0.f};
    floatx4 acc1 = {0.f, 0.f, 0.f, 0.f};
    #pragma unroll
    for (int s = 0; s < 2; ++s) {
        const float4* p = (const float4*)(arow + s * 32);
        float4 lo = p[0], hi = p[1];
        short8 a;
        a[0]=f2bf(lo.x); a[1]=f2bf(lo.y); a[2]=f2bf(lo.z); a[3]=f2bf(lo.w);
        a[4]=f2bf(hi.x); a[5]=f2bf(hi.y); a[6]=f2bf(hi.z); a[7]=f2bf(hi.w);
        acc0 = __builtin_amdgcn_mfma_f32_16x16x32_bf16(a, bfr[s][0], acc0, 0, 0, 0);
        acc1 = __builtin_amdgcn_mfma_f32_16x16x32_bf16(a, bfr[s][1], acc1, 0, 0, 0);
    }
    #pragma unroll
    for (int i = 0; i < 4; ++i) {
        const int orow = out_map[mapbase + m0 + quad * 4 + i];
        float* po = out + (long long)orow * COUT;
        atomicAdd(po + col,      acc0[i]);
        atomicAdd(po + col + 16, acc1[i]);
    }
}

// ---------------- feats f32 -> bf16 (8 elems/thread) -----------------------
__global__ __launch_bounds__(256) void feats_to_bf16_kernel(
    const float* __restrict__ f, ushort* __restrict__ b)
{
    const int t = blockIdx.x * blockDim.x + threadIdx.x;   // [0, NIN*CIN/8)
    const float4* p = (const float4*)(f + (size_t)t * 8);
    float4 lo = p[0], hi = p[1];
    short8 v;
    v[0]=f2bf(lo.x); v[1]=f2bf(lo.y); v[2]=f2bf(lo.z); v[3]=f2bf(lo.w);
    v[4]=f2bf(hi.x); v[5]=f2bf(hi.y); v[6]=f2bf(hi.z); v[7]=f2bf(hi.w);
    *(short8*)(b + (size_t)t * 8) = v;
}

// ---------------- fp16 accum -> f32 out (4 half2 / thread) -----------------
__global__ __launch_bounds__(256) void h2_to_f32_kernel(
    const __half2* __restrict__ acc, float* __restrict__ out)
{
    const int t = blockIdx.x * blockDim.x + threadIdx.x;   // [0, NOUT*16/4)
    const __half2* p = acc + (size_t)t * 4;
    float2 f0 = __half22float2(p[0]);
    float2 f1 = __half22float2(p[1]);
    float2 f2 = __half22float2(p[2]);
    float2 f3 = __half22float2(p[3]);
    float4* o = (float4*)out + (size_t)t * 2;
    o[0] = make_float4(f0.x, f0.y, f1.x, f1.y);
    o[1] = make_float4(f2.x, f2.y, f3.x, f3.y);
}

extern "C" void kernel_launch(void* const* d_in, const int* in_sizes, int n_in,
                              void* d_out, int out_size, void* d_ws, size_t ws_size,
                              hipStream_t stream) {
    const float* feats   = (const float*)d_in[0];
    const float* weight  = (const float*)d_in[1];
    const int*   in_map  = (const int*)d_in[2];
    const int*   out_map = (const int*)d_in[3];
    float*       out     = (float*)d_out;

    dim3 grid((TILES + WPB - 1) / WPB, KOFF);
    dim3 block(WPB * 64);

    if (ws_size >= ACC_BYTES + FEATS_BYTES) {
        __half2* accum    = (__half2*)d_ws;
        ushort*  feats_bf = (ushort*)((char*)d_ws + ACC_BYTES);
        hipMemsetAsync(accum, 0, ACC_BYTES, stream);
        feats_to_bf16_kernel<<<(NIN * CIN / 8) / 256, 256, 0, stream>>>(feats, feats_bf);
        spconv_fp16acc_kernel<true><<<grid, block, 0, stream>>>(
            feats, feats_bf, weight, in_map, out_map, accum);
        h2_to_f32_kernel<<<(NOUT * 16 / 4) / 256, 256, 0, stream>>>(accum, out);
    } else if (ws_size >= ACC_BYTES) {
        __half2* accum = (__half2*)d_ws;
        hipMemsetAsync(accum, 0, ACC_BYTES, stream);
        spconv_fp16acc_kernel<false><<<grid, block, 0, stream>>>(
            feats, nullptr, weight, in_map, out_map, accum);
        h2_to_f32_kernel<<<(NOUT * 16 / 4) / 256, 256, 0, stream>>>(accum, out);
    } else {
        hipMemsetAsync(d_out, 0, (size_t)out_size * sizeof(float), stream);
        spconv_f32atomic_kernel<<<grid, block, 0, stream>>>(
            feats, weight, in_map, out_map, out);
    }
}